// Round 9
// baseline (2132.160 us; speedup 1.0000x reference)
//
#include <hip/hip_runtime.h>
#include <hip/hip_bf16.h>
#include <math.h>

typedef __bf16 bf16_t;
typedef __bf16 bf16x8 __attribute__((ext_vector_type(8)));
typedef float  f32x4  __attribute__((ext_vector_type(4)));
typedef float  f32x16 __attribute__((ext_vector_type(16)));

#define AS1 __attribute__((address_space(1)))
#define AS3 __attribute__((address_space(3)))

__device__ __forceinline__ void gload_lds16(const bf16_t* g, char* l) {
  __builtin_amdgcn_global_load_lds((const AS1 void*)g, (AS3 void*)l, 16, 0, 0);
}

static constexpr int N_ROWS = 8192;
static constexpr int DDIM   = 4096;
static constexpr int KEXP   = 8;
static constexpr int FHID   = 1024;
static constexpr int KD     = 8192;   // inner dim of both GEMMs (2D and K*F)

// ---------------- routing: weights = softmax(h_mask @ Wr^T + br) ----------------
__global__ __launch_bounds__(256)
void routing_kernel(const float* __restrict__ hm, const float* __restrict__ Wr,
                    const float* __restrict__ br, float* __restrict__ wgt) {
  const int n = blockIdx.x;
  const int t = threadIdx.x;
  const int wid = t >> 6;
  const float4* row = (const float4*)(hm + (size_t)n * DDIM);
  float4 x[4];
#pragma unroll
  for (int j = 0; j < 4; ++j) x[j] = row[t + j * 256];
  __shared__ float red[KEXP][4];
  float part[KEXP];
#pragma unroll
  for (int k = 0; k < KEXP; ++k) {
    const float4* wr = (const float4*)(Wr + (size_t)k * DDIM);
    float s = 0.f;
#pragma unroll
    for (int j = 0; j < 4; ++j) {
      float4 w4 = wr[t + j * 256];
      s += x[j].x * w4.x + x[j].y * w4.y + x[j].z * w4.z + x[j].w * w4.w;
    }
#pragma unroll
    for (int off = 32; off > 0; off >>= 1) s += __shfl_down(s, off);
    part[k] = s;
  }
  if ((t & 63) == 0) {
#pragma unroll
    for (int k = 0; k < KEXP; ++k) red[k][wid] = part[k];
  }
  __syncthreads();
  if (t == 0) {
    float lg[KEXP];
    float mx = -1e30f;
#pragma unroll
    for (int k = 0; k < KEXP; ++k) {
      lg[k] = red[k][0] + red[k][1] + red[k][2] + red[k][3] + br[k];
      mx = fmaxf(mx, lg[k]);
    }
    float sum = 0.f;
#pragma unroll
    for (int k = 0; k < KEXP; ++k) { lg[k] = expf(lg[k] - mx); sum += lg[k]; }
    float inv = 1.f / sum;
#pragma unroll
    for (int k = 0; k < KEXP; ++k) wgt[(size_t)n * KEXP + k] = lg[k] * inv;
  }
}

// ---------------- conversions to bf16 ----------------
__device__ __forceinline__ bf16x8 cvt8(float4 f0, float4 f1) {
  bf16x8 o;
  o[0] = (bf16_t)f0.x; o[1] = (bf16_t)f0.y; o[2] = (bf16_t)f0.z; o[3] = (bf16_t)f0.w;
  o[4] = (bf16_t)f1.x; o[5] = (bf16_t)f1.y; o[6] = (bf16_t)f1.z; o[7] = (bf16_t)f1.w;
  return o;
}

// A[n][0:4096]=h_anchor, A[n][4096:8192]=h_mask   (concat, bf16)
__global__ __launch_bounds__(256)
void conv_cond_kernel(const float* __restrict__ ha, const float* __restrict__ hm,
                      bf16_t* __restrict__ A) {
  size_t c = (size_t)blockIdx.x * 256 + threadIdx.x;  // chunk of 8 elements
  int n   = (int)(c >> 10);                           // 1024 chunks per row of 8192
  int pos = ((int)c & 1023) * 8;
  const float* src = (pos < DDIM) ? ha + (size_t)n * DDIM + pos
                                  : hm + (size_t)n * DDIM + (pos - DDIM);
  float4 f0 = ((const float4*)src)[0];
  float4 f1 = ((const float4*)src)[1];
  *(bf16x8*)(A + c * 8) = cvt8(f0, f1);
}

// straight fp32 -> bf16 cast (W1: already [K*F][2D] row-major)
__global__ __launch_bounds__(256)
void conv_cast_kernel(const float* __restrict__ in, bf16_t* __restrict__ out) {
  size_t c = (size_t)blockIdx.x * 256 + threadIdx.x;
  float4 f0 = ((const float4*)(in + c * 8))[0];
  float4 f1 = ((const float4*)(in + c * 8))[1];
  *(bf16x8*)(out + c * 8) = cvt8(f0, f1);
}

// W2[k][d][f] -> B2[d][k*F+f]  (bf16)
__global__ __launch_bounds__(256)
void conv_w2_kernel(const float* __restrict__ W2, bf16_t* __restrict__ B2) {
  size_t c = (size_t)blockIdx.x * 256 + threadIdx.x;  // over K*D*F/8
  int f8 = (int)(c & 127);
  int d  = (int)((c >> 7) & 4095);
  int k  = (int)(c >> 19);
  const float* src = W2 + ((size_t)k * DDIM + d) * FHID + f8 * 8;
  float4 f0 = ((const float4*)src)[0];
  float4 f1 = ((const float4*)src)[1];
  *(bf16x8*)(B2 + (size_t)d * KD + k * FHID + f8 * 8) = cvt8(f0, f1);
}

// ---------------- 256x256 GEMM v9: 32x32x16 MFMA + fragment-major LDS ----------------
// BK=64, 2 LDS buffers (64 KB each), 8 waves (2Mx4N), per-wave tile 128x64 = 4x2
// tiles of 32x32, acc[4][2] f32x16. Phase = k-step16 (4/tile): 6 ds_read_b128 +
// lgkm countdown(3/2/1/0) + 8 independent 32x32 MFMA.
// FRAGMENT-MAJOR LDS: each 1KB block stored in lane order (base + lane*16); the
// per-lane GLOBAL source of global_load_lds does the gather (lane l -> row l&31,
// k (l>>5)*8). Reads are base+imm, lane-stride 16B -> conflict-free, no swizzle.
//   A region: h*16384 + s*4096 + mi*1024   (h = 128-row half, s = k-step, mi = 32-row)
//   B region: 32768 + s*8192 + n*1024      (n = 32-col group 0..7)
// Staging rotation (all into the OPPOSITE buffer -> no same-buffer staging ever):
//   s0: A-lo(t+1)  s1: B-lo(t+1)+GATE  s2: A-hi(t+1)  s3: B-hi(t+1)+GATE
// (lo/hi = k-steps {0,1}/{2,3}). GATE = vmcnt(4)+s_barrier (2 barriers/tile).
// Rendezvous audit: gate at end-s3(t-1) retires+publishes A-lo(t),B-lo(t) (issued
// t-1 s0/s1) before t s0 reads; gate at end-s1(t) retires+publishes A-hi(t),B-hi(t)
// before t s2 reads. Stage targets hold tile t-1 data whose last reads retired
// before a barrier both waves passed. Landing slack >= 2 phases (~2100cy > 900 HBM).
// Modular tau wrap keeps vmcnt counts uniform incl. tail (round-3 lesson).
// MODE 1: epilogue = +b1, exact GELU, *w[n][col>>10], store bf16 (H1s)
// MODE 2: epilogue = + sum_k w[n][k]*b2[k][col], store fp32 (out)
template <int MODE, int NCOLS>
__global__ __launch_bounds__(512, 2)
void gemm256_kernel(const bf16_t* __restrict__ Amat, const bf16_t* __restrict__ Bmat,
                    void* __restrict__ Cout, const float* __restrict__ bias,
                    const float* __restrict__ wgt) {
  constexpr int BK = 64;
  constexpr int NKT = KD / BK;           // 128 K-tiles
  __shared__ char lds_raw[2 * 65536];    // 128 KB

  const int tid  = threadIdx.x;
  const int wid  = tid >> 6;
  const int lane = tid & 63;
  const int wr   = wid >> 2;             // 0..1  (M half)
  const int wc   = wid & 3;              // 0..3  (N quarter)

  // ---- 2-D concurrency-window block remap (16x16 window, 4x8 per XCD)
  constexpr int NBN    = NCOLS / 256;    // 32 (GEMM1) or 16 (GEMM2)
  constexpr int NWIN_N = NBN / 16;       // 2 or 1
  const int bid = blockIdx.x;
  const int w   = bid >> 8;
  const int sl  = bid & 255;
  const int xcd = sl & 7;
  const int cu  = sl >> 3;
  const int wm  = w / NWIN_N, wn = w % NWIN_N;
  const int bm  = wm * 16 + ((xcd >> 1) << 2) + (cu & 3);
  const int bn  = wn * 16 + ((xcd & 1) << 3) + (cu >> 2);
  const int arow0 = bm * 256;
  const int brow0 = bn * 256;

  // ---- staging descriptors: wave wid stages blocks b0=2*wid, b1=2*wid+1 of each group
  const int b0 = 2 * wid, b1 = 2 * wid + 1;
  // A block b (k-lo group): s=b>>3, h=(b>>2)&1, m=b&3
  const int dA0 = ((b0 >> 2) & 1) * 16384 + (b0 >> 3) * 4096 + (b0 & 3) * 1024;
  const int dA1 = ((b1 >> 2) & 1) * 16384 + (b1 >> 3) * 4096 + (b1 & 3) * 1024;
  // B block b (k-lo group): s=b>>3, n=b&7
  const int dB0 = 32768 + (b0 >> 3) * 8192 + (b0 & 7) * 1024;
  const int dB1 = 32768 + (b1 >> 3) * 8192 + (b1 & 7) * 1024;
  const bf16_t* srcA0 = Amat + (size_t)(arow0 + ((b0 >> 2) & 1) * 128 + (b0 & 3) * 32 + (lane & 31)) * KD
                        + (b0 >> 3) * 16 + (lane >> 5) * 8;
  const bf16_t* srcA1 = Amat + (size_t)(arow0 + ((b1 >> 2) & 1) * 128 + (b1 & 3) * 32 + (lane & 31)) * KD
                        + (b1 >> 3) * 16 + (lane >> 5) * 8;
  const bf16_t* srcB0 = Bmat + (size_t)(brow0 + (b0 & 7) * 32 + (lane & 31)) * KD
                        + (b0 >> 3) * 16 + (lane >> 5) * 8;
  const bf16_t* srcB1 = Bmat + (size_t)(brow0 + (b1 & 7) * 32 + (lane & 31)) * KD
                        + (b1 >> 3) * 16 + (lane >> 5) * 8;
  // k-hi variants: src + 32 elements, dst + 8192 (A) / + 16384 (B)

  f32x16 acc[4][2];
#pragma unroll
  for (int mi = 0; mi < 4; ++mi)
#pragma unroll
    for (int nj = 0; nj < 2; ++nj)
#pragma unroll
      for (int r = 0; r < 16; ++r) acc[mi][nj][r] = 0.f;

  // ---- prologue: stage tile 0 (all 4 groups) into buf0, drain, rendezvous
  gload_lds16(srcA0, lds_raw + dA0);
  gload_lds16(srcA1, lds_raw + dA1);
  gload_lds16(srcB0, lds_raw + dB0);
  gload_lds16(srcB1, lds_raw + dB1);
  gload_lds16(srcA0 + 32, lds_raw + dA0 + 8192);
  gload_lds16(srcA1 + 32, lds_raw + dA1 + 8192);
  gload_lds16(srcB0 + 32, lds_raw + dB0 + 16384);
  gload_lds16(srcB1 + 32, lds_raw + dB1 + 16384);
  asm volatile("s_waitcnt vmcnt(0)" ::: "memory");
  __builtin_amdgcn_s_barrier();
  __builtin_amdgcn_sched_barrier(0);

#define SB __builtin_amdgcn_sched_barrier(0);
#define MM(MI)                                                                  \
    acc[MI][0] = __builtin_amdgcn_mfma_f32_32x32x16_bf16(aq[MI], qb0,           \
                                                         acc[MI][0], 0, 0, 0);  \
    acc[MI][1] = __builtin_amdgcn_mfma_f32_32x32x16_bf16(aq[MI], qb1,           \
                                                         acc[MI][1], 0, 0, 0);

#define PH(SS, STG0, STG1, GATE)                                                \
  {                                                                             \
    STG0;                                                                       \
    STG1;                                                                       \
    SB                                                                          \
    bf16x8 qb0 = *(const bf16x8*)(bB + (SS) * 8192);                            \
    bf16x8 qb1 = *(const bf16x8*)(bB + (SS) * 8192 + 1024);                     \
    SB                                                                          \
    bf16x8 aq[4];                                                               \
    aq[0] = *(const bf16x8*)(bA + (SS) * 4096);                                 \
    SB                                                                          \
    aq[1] = *(const bf16x8*)(bA + (SS) * 4096 + 1024);                          \
    SB                                                                          \
    aq[2] = *(const bf16x8*)(bA + (SS) * 4096 + 2048);                          \
    SB                                                                          \
    aq[3] = *(const bf16x8*)(bA + (SS) * 4096 + 3072);                          \
    SB                                                                          \
    __builtin_amdgcn_s_setprio(1);                                              \
    asm volatile("s_waitcnt lgkmcnt(3)" ::: "memory");                          \
    SB                                                                          \
    MM(0)                                                                       \
    SB                                                                          \
    asm volatile("s_waitcnt lgkmcnt(2)" ::: "memory");                          \
    SB                                                                          \
    MM(1)                                                                       \
    SB                                                                          \
    asm volatile("s_waitcnt lgkmcnt(1)" ::: "memory");                          \
    SB                                                                          \
    MM(2)                                                                       \
    SB                                                                          \
    asm volatile("s_waitcnt lgkmcnt(0)" ::: "memory");                          \
    SB                                                                          \
    MM(3)                                                                       \
    SB                                                                          \
    __builtin_amdgcn_s_setprio(0);                                              \
    if (GATE) {                                                                 \
      asm volatile("s_waitcnt vmcnt(4)" ::: "memory");                          \
      SB                                                                        \
      __builtin_amdgcn_s_barrier();                                             \
      SB                                                                        \
    }                                                                           \
  }

  int cur = 0;
  for (int t = 0; t < NKT; ++t) {
    const size_t ko = (size_t)((t + 1) & (NKT - 1)) * BK;   // next-tile k offset
    char* nb = lds_raw + (cur ^ 65536);                     // staging buffer
    const char* bA = lds_raw + cur + wr * 16384 + lane * 16;
    const char* bB = lds_raw + cur + 32768 + wc * 2048 + lane * 16;
    PH(0, gload_lds16(srcA0 + ko, nb + dA0),
          gload_lds16(srcA1 + ko, nb + dA1), 0)
    PH(1, gload_lds16(srcB0 + ko, nb + dB0),
          gload_lds16(srcB1 + ko, nb + dB1), 1)
    PH(2, gload_lds16(srcA0 + ko + 32, nb + dA0 + 8192),
          gload_lds16(srcA1 + ko + 32, nb + dA1 + 8192), 0)
    PH(3, gload_lds16(srcB0 + ko + 32, nb + dB0 + 16384),
          gload_lds16(srcB1 + ko + 32, nb + dB1 + 16384), 1)
    cur ^= 65536;
  }
#undef PH
#undef MM
#undef SB

  // ---- epilogue.  32x32 C/D layout: col = lane&31, row = (reg&3)+8*(reg>>2)+4*(lane>>5)
  const int rbase = arow0 + wr * 128 + ((lane >> 5) << 2);
  const int cbase = brow0 + wc * 64 + (lane & 31);

  if constexpr (MODE == 1) {
    bf16_t* __restrict__ H = (bf16_t*)Cout;
    const int kexp = brow0 >> 10;  // expert is block-uniform (256 | 1024)
    float bv[2] = {bias[cbase], bias[cbase + 32]};
#pragma unroll
    for (int mi = 0; mi < 4; ++mi)
#pragma unroll
      for (int r = 0; r < 16; ++r) {
        int n = rbase + mi * 32 + (r & 3) + 8 * (r >> 2);
        float wn4 = wgt[(size_t)n * KEXP + kexp];
#pragma unroll
        for (int nj = 0; nj < 2; ++nj) {
          float x = acc[mi][nj][r] + bv[nj];
          float g = 0.5f * x * (1.f + erff(x * 0.70710678118654752f));  // exact GELU
          H[(size_t)n * KD + cbase + nj * 32] = (bf16_t)(g * wn4);
        }
      }
  } else {
    float* __restrict__ O = (float*)Cout;
    float bc0[KEXP], bc1[KEXP];
#pragma unroll
    for (int k = 0; k < KEXP; ++k) {
      bc0[k] = bias[(size_t)k * NCOLS + cbase];
      bc1[k] = bias[(size_t)k * NCOLS + cbase + 32];
    }
#pragma unroll
    for (int mi = 0; mi < 4; ++mi)
#pragma unroll
      for (int r = 0; r < 16; ++r) {
        int n = rbase + mi * 32 + (r & 3) + 8 * (r >> 2);
        const float4* wp = (const float4*)(wgt + (size_t)n * KEXP);
        float4 wa = wp[0], wb = wp[1];
        float w8[KEXP] = {wa.x, wa.y, wa.z, wa.w, wb.x, wb.y, wb.z, wb.w};
        float s0 = 0.f, s1 = 0.f;
#pragma unroll
        for (int k = 0; k < KEXP; ++k) { s0 += w8[k] * bc0[k]; s1 += w8[k] * bc1[k]; }
        O[(size_t)n * NCOLS + cbase]      = acc[mi][0][r] + s0;
        O[(size_t)n * NCOLS + cbase + 32] = acc[mi][1][r] + s1;
      }
  }
}

extern "C" void kernel_launch(void* const* d_in, const int* in_sizes, int n_in,
                              void* d_out, int out_size, void* d_ws, size_t ws_size,
                              hipStream_t stream) {
  const float* h_anchor = (const float*)d_in[0];
  const float* h_mask   = (const float*)d_in[1];
  const float* Wr       = (const float*)d_in[2];
  const float* br       = (const float*)d_in[3];
  const float* W1       = (const float*)d_in[4];
  const float* b1       = (const float*)d_in[5];
  const float* W2       = (const float*)d_in[6];
  const float* b2       = (const float*)d_in[7];
  float* out = (float*)d_out;

  char* ws = (char*)d_ws;
  bf16_t* Abf  = (bf16_t*)(ws);                       // [8192][8192] bf16 = 128 MB
  bf16_t* W1bf = (bf16_t*)(ws + ((size_t)128 << 20)); // [8192][8192] bf16 = 128 MB
  bf16_t* W2bf = (bf16_t*)(ws + ((size_t)256 << 20)); // [4096][8192] bf16 =  64 MB
  bf16_t* H1s  = (bf16_t*)(ws + ((size_t)320 << 20)); // [8192][8192] bf16 = 128 MB
  float*  wgt  = (float*) (ws + ((size_t)448 << 20)); // [8192][8]   fp32 = 256 KB

  routing_kernel<<<N_ROWS, 256, 0, stream>>>(h_mask, Wr, br, wgt);
  conv_cond_kernel<<<(N_ROWS * KD / 8) / 256, 256, 0, stream>>>(h_anchor, h_mask, Abf);
  conv_cast_kernel<<<(KEXP * FHID * 2 * DDIM / 8) / 256, 256, 0, stream>>>(W1, W1bf);
  conv_w2_kernel<<<(KEXP * DDIM * FHID / 8) / 256, 256, 0, stream>>>(W2, W2bf);

  gemm256_kernel<1, 8192><<<(N_ROWS / 256) * (KD / 256), 512, 0, stream>>>(
      Abf, W1bf, (void*)H1s, b1, wgt);
  gemm256_kernel<2, 4096><<<(N_ROWS / 256) * (DDIM / 256), 512, 0, stream>>>(
      H1s, W2bf, (void*)out, b2, wgt);
}

// Round 10
// 1639.389 us; speedup vs baseline: 1.3006x; 1.3006x over previous
//
#include <hip/hip_runtime.h>
#include <hip/hip_bf16.h>
#include <math.h>

typedef __bf16 bf16_t;
typedef __bf16 bf16x4 __attribute__((ext_vector_type(4)));
typedef __bf16 bf16x8 __attribute__((ext_vector_type(8)));
typedef float  f32x4  __attribute__((ext_vector_type(4)));
typedef float  f32x16 __attribute__((ext_vector_type(16)));

#define AS1 __attribute__((address_space(1)))
#define AS3 __attribute__((address_space(3)))

__device__ __forceinline__ void gload_lds16(const bf16_t* g, char* l) {
  __builtin_amdgcn_global_load_lds((const AS1 void*)g, (AS3 void*)l, 16, 0, 0);
}

static constexpr int N_ROWS = 8192;
static constexpr int DDIM   = 4096;
static constexpr int KEXP   = 8;
static constexpr int FHID   = 1024;
static constexpr int KD     = 8192;   // inner dim of both GEMMs (2D and K*F)
static constexpr int NKT    = KD / 64; // 128 k-tiles

// ================= packed fragment-major tile format =================
// Per (256-row block, 64-k tile): 32 KB contiguous.
// A-layout byte offset (row R in 0..255, k in 0..63):
//   (R>>7)*16384 + ((k>>4)&3)*4096 + ((R>>5)&3)*1024 + ((k>>3)&1)*512 + (R&31)*16 + (k&7)*2
// B-layout byte offset (col C in 0..255, k in 0..63):
//   ((k>>4)&3)*8192 + ((C>>5)&7)*1024 + ((k>>3)&1)*512 + (C&31)*16 + (k&7)*2
// These equal the GEMM's LDS layout, so global_load_lds moves bytes 1:1
// (contiguous 1KB per wave, linear LDS dest) and every ds_read is lane*16
// (conflict-free by construction). MFMA 32x32x16 operand: lane l = row/col l&31,
// k-half l>>5 (verified by r9's passing refcheck).

// ---------------- routing: weights = softmax(h_mask @ Wr^T + br) ----------------
__global__ __launch_bounds__(256)
void routing_kernel(const float* __restrict__ hm, const float* __restrict__ Wr,
                    const float* __restrict__ br, float* __restrict__ wgt) {
  const int n = blockIdx.x;
  const int t = threadIdx.x;
  const int wid = t >> 6;
  const float4* row = (const float4*)(hm + (size_t)n * DDIM);
  float4 x[4];
#pragma unroll
  for (int j = 0; j < 4; ++j) x[j] = row[t + j * 256];
  __shared__ float red[KEXP][4];
  float part[KEXP];
#pragma unroll
  for (int k = 0; k < KEXP; ++k) {
    const float4* wr = (const float4*)(Wr + (size_t)k * DDIM);
    float s = 0.f;
#pragma unroll
    for (int j = 0; j < 4; ++j) {
      float4 w4 = wr[t + j * 256];
      s += x[j].x * w4.x + x[j].y * w4.y + x[j].z * w4.z + x[j].w * w4.w;
    }
#pragma unroll
    for (int off = 32; off > 0; off >>= 1) s += __shfl_down(s, off);
    part[k] = s;
  }
  if ((t & 63) == 0) {
#pragma unroll
    for (int k = 0; k < KEXP; ++k) red[k][wid] = part[k];
  }
  __syncthreads();
  if (t == 0) {
    float lg[KEXP];
    float mx = -1e30f;
#pragma unroll
    for (int k = 0; k < KEXP; ++k) {
      lg[k] = red[k][0] + red[k][1] + red[k][2] + red[k][3] + br[k];
      mx = fmaxf(mx, lg[k]);
    }
    float sum = 0.f;
#pragma unroll
    for (int k = 0; k < KEXP; ++k) { lg[k] = expf(lg[k] - mx); sum += lg[k]; }
    float inv = 1.f / sum;
#pragma unroll
    for (int k = 0; k < KEXP; ++k) wgt[(size_t)n * KEXP + k] = lg[k] * inv;
  }
}

// ---------------- pack kernels: fp32 source -> bf16 packed tiles ----------------
__device__ __forceinline__ bf16x4 cvt4(float4 v) {
  bf16x4 o;
  o[0] = (bf16_t)v.x; o[1] = (bf16_t)v.y; o[2] = (bf16_t)v.z; o[3] = (bf16_t)v.w;
  return o;
}

// A-pack from concat(h_anchor, h_mask). grid = 32 bm x 128 t.
__global__ __launch_bounds__(256)
void pack_cond_kernel(const float* __restrict__ ha, const float* __restrict__ hm,
                      bf16_t* __restrict__ Apk) {
  const int bm = blockIdx.x >> 7, t = blockIdx.x & 127;
  const int tid = threadIdx.x;
  const float* src = (t < 64) ? ha : hm;
  const int cb = (t & 63) * 64;
  __shared__ char pb[32768];
#pragma unroll
  for (int i = 0; i < 16; ++i) {
    int u = i * 256 + tid;
    int r = u >> 4, c = (u & 15) * 4;
    float4 v = *(const float4*)(src + (size_t)(bm * 256 + r) * DDIM + cb + c);
    int off = ((r >> 7) & 1) * 16384 + ((c >> 4) & 3) * 4096 + ((r >> 5) & 3) * 1024
            + ((c >> 3) & 1) * 512 + (r & 31) * 16 + (c & 7) * 2;
    *(bf16x4*)(pb + off) = cvt4(v);
  }
  __syncthreads();
  char* dst = (char*)Apk + (size_t)blockIdx.x * 32768;
#pragma unroll
  for (int i = 0; i < 8; ++i) {
    int off = i * 4096 + tid * 16;
    *(float4*)(dst + off) = *(const float4*)(pb + off);
  }
}

// B-pack from W1 (flat [8192][8192]). grid = 32 bn x 128 t.
__global__ __launch_bounds__(256)
void pack_w1_kernel(const float* __restrict__ W1, bf16_t* __restrict__ Bpk) {
  const int bn = blockIdx.x >> 7, t = blockIdx.x & 127;
  const int tid = threadIdx.x;
  __shared__ char pb[32768];
#pragma unroll
  for (int i = 0; i < 16; ++i) {
    int u = i * 256 + tid;
    int r = u >> 4, c = (u & 15) * 4;
    float4 v = *(const float4*)(W1 + (size_t)(bn * 256 + r) * KD + t * 64 + c);
    int off = ((c >> 4) & 3) * 8192 + ((r >> 5) & 7) * 1024
            + ((c >> 3) & 1) * 512 + (r & 31) * 16 + (c & 7) * 2;
    *(bf16x4*)(pb + off) = cvt4(v);
  }
  __syncthreads();
  char* dst = (char*)Bpk + (size_t)blockIdx.x * 32768;
#pragma unroll
  for (int i = 0; i < 8; ++i) {
    int off = i * 4096 + tid * 16;
    *(float4*)(dst + off) = *(const float4*)(pb + off);
  }
}

// B-pack from W2 [K][D][F] with d as output col, k-dim = k*F+f. grid = 16 bn x 128 t.
__global__ __launch_bounds__(256)
void pack_w2_kernel(const float* __restrict__ W2, bf16_t* __restrict__ Bpk) {
  const int bn = blockIdx.x >> 7, t = blockIdx.x & 127;
  const int tid = threadIdx.x;
  const int ke = t >> 4, f0 = (t & 15) * 64;
  __shared__ char pb[32768];
#pragma unroll
  for (int i = 0; i < 16; ++i) {
    int u = i * 256 + tid;
    int r = u >> 4, c = (u & 15) * 4;
    float4 v = *(const float4*)(W2 + ((size_t)ke * DDIM + bn * 256 + r) * FHID + f0 + c);
    int off = ((c >> 4) & 3) * 8192 + ((r >> 5) & 7) * 1024
            + ((c >> 3) & 1) * 512 + (r & 31) * 16 + (c & 7) * 2;
    *(bf16x4*)(pb + off) = cvt4(v);
  }
  __syncthreads();
  char* dst = (char*)Bpk + (size_t)blockIdx.x * 32768;
#pragma unroll
  for (int i = 0; i < 8; ++i) {
    int off = i * 4096 + tid * 16;
    *(float4*)(dst + off) = *(const float4*)(pb + off);
  }
}

// ---------------- 256x256 GEMM v10: 32x32x16 MFMA + packed coalesced staging --------
// Inputs are PACKED tiles (32 KB per (block,k-tile), byte layout == LDS layout).
// BK=64, 2 LDS buffers (64 KB), 8 waves (2Mx4N), acc[4][2] f32x16.
// Phase = k-step16: 6 ds_read_b128 (lane*16, conflict-free) + lgkm countdown + 8 MFMA.
// Staging: 2 contiguous-1KB/wave gloads per phase into the OPPOSITE buffer.
//   s0: A s{0,1} both h | s1: B s{0,1} + GATE | s2: A s{2,3} | s3: B s{2,3} + GATE
// GATE = vmcnt(4)+barrier (2 barriers/tile). Gate(s1,t) publishes A-hi(t),B-hi(t)
// before s2(t) reads; gate(s3,t) publishes A-lo(t+1),B-lo(t+1) before s0(t+1).
// Stage targets hold tile t-1 data whose reads retired before the barrier both
// waves passed (r9 schedule, tripwire-proven). Modular tau wrap (round-3 lesson).
// MODE 1: +b1, exact GELU, *w[n][expert], store bf16 PACKED (Hpk, GEMM2's A)
// MODE 2: + sum_k w[n][k]*b2[k][col], store fp32 row-major (out)
template <int MODE, int NCOLS>
__global__ __launch_bounds__(512, 2)
void gemm256_kernel(const bf16_t* __restrict__ Apk, const bf16_t* __restrict__ Bpk,
                    void* __restrict__ Cout, const float* __restrict__ bias,
                    const float* __restrict__ wgt) {
  __shared__ char lds_raw[2 * 65536];    // 128 KB

  const int tid  = threadIdx.x;
  const int wid  = tid >> 6;
  const int lane = tid & 63;
  const int wr   = wid >> 2;             // 0..1  (M half)
  const int wc   = wid & 3;              // 0..3  (N quarter)

  // ---- 2-D concurrency-window block remap (16x16 window, 4x8 per XCD)
  constexpr int NBN    = NCOLS / 256;    // 32 (GEMM1) or 16 (GEMM2)
  constexpr int NWIN_N = NBN / 16;       // 2 or 1
  const int bid = blockIdx.x;
  const int w   = bid >> 8;
  const int sl  = bid & 255;
  const int xcd = sl & 7;
  const int cu  = sl >> 3;
  const int wm  = w / NWIN_N, wn = w % NWIN_N;
  const int bm  = wm * 16 + ((xcd >> 1) << 2) + (cu & 3);
  const int bn  = wn * 16 + ((xcd & 1) << 3) + (cu >> 2);
  const int arow0 = bm * 256;
  const int brow0 = bn * 256;

  // ---- staging bases: contiguous packed tiles; per-lane src, wave-uniform dst
  const size_t abase = (size_t)bm * NKT * 16384;   // elements
  const size_t bbase = (size_t)bn * NKT * 16384;
  const size_t selo  = (size_t)(wid * 512 + lane * 8);  // element offset in 8KB chunk
  const int    dsto  = wid << 10;                       // byte offset (wave-uniform)

  f32x16 acc[4][2];
#pragma unroll
  for (int mi = 0; mi < 4; ++mi)
#pragma unroll
    for (int nj = 0; nj < 2; ++nj)
#pragma unroll
      for (int r = 0; r < 16; ++r) acc[mi][nj][r] = 0.f;

#define STG_A(I, TAU, NB)                                                        \
  gload_lds16(Apk + abase + (size_t)((TAU) & (NKT - 1)) * 16384 + (I) * 4096 + selo, \
              (NB) + (I) * 8192 + dsto);
#define STG_B(I, TAU, NB)                                                        \
  gload_lds16(Bpk + bbase + (size_t)((TAU) & (NKT - 1)) * 16384 + (I) * 4096 + selo, \
              (NB) + 32768 + (I) * 8192 + dsto);

  // ---- prologue: stage tile 0 into buf0, drain, rendezvous
  STG_A(0, 0, lds_raw) STG_A(2, 0, lds_raw) STG_B(0, 0, lds_raw) STG_B(1, 0, lds_raw)
  STG_A(1, 0, lds_raw) STG_A(3, 0, lds_raw) STG_B(2, 0, lds_raw) STG_B(3, 0, lds_raw)
  asm volatile("s_waitcnt vmcnt(0)" ::: "memory");
  __builtin_amdgcn_s_barrier();
  __builtin_amdgcn_sched_barrier(0);

#define SB __builtin_amdgcn_sched_barrier(0);
#define MM(MI)                                                                  \
    acc[MI][0] = __builtin_amdgcn_mfma_f32_32x32x16_bf16(aq[MI], qb0,           \
                                                         acc[MI][0], 0, 0, 0);  \
    acc[MI][1] = __builtin_amdgcn_mfma_f32_32x32x16_bf16(aq[MI], qb1,           \
                                                         acc[MI][1], 0, 0, 0);

#define PH(SS, STG0, STG1, GATE)                                                \
  {                                                                             \
    STG0;                                                                       \
    STG1;                                                                       \
    SB                                                                          \
    bf16x8 qb0 = *(const bf16x8*)(bB + (SS) * 8192);                            \
    bf16x8 qb1 = *(const bf16x8*)(bB + (SS) * 8192 + 1024);                     \
    SB                                                                          \
    bf16x8 aq[4];                                                               \
    aq[0] = *(const bf16x8*)(bA + (SS) * 4096);                                 \
    SB                                                                          \
    aq[1] = *(const bf16x8*)(bA + (SS) * 4096 + 1024);                          \
    SB                                                                          \
    aq[2] = *(const bf16x8*)(bA + (SS) * 4096 + 2048);                          \
    SB                                                                          \
    aq[3] = *(const bf16x8*)(bA + (SS) * 4096 + 3072);                          \
    SB                                                                          \
    __builtin_amdgcn_s_setprio(1);                                              \
    asm volatile("s_waitcnt lgkmcnt(3)" ::: "memory");                          \
    SB                                                                          \
    MM(0)                                                                       \
    SB                                                                          \
    asm volatile("s_waitcnt lgkmcnt(2)" ::: "memory");                          \
    SB                                                                          \
    MM(1)                                                                       \
    SB                                                                          \
    asm volatile("s_waitcnt lgkmcnt(1)" ::: "memory");                          \
    SB                                                                          \
    MM(2)                                                                       \
    SB                                                                          \
    asm volatile("s_waitcnt lgkmcnt(0)" ::: "memory");                          \
    SB                                                                          \
    MM(3)                                                                       \
    SB                                                                          \
    __builtin_amdgcn_s_setprio(0);                                              \
    if (GATE) {                                                                 \
      asm volatile("s_waitcnt vmcnt(4)" ::: "memory");                          \
      SB                                                                        \
      __builtin_amdgcn_s_barrier();                                             \
      SB                                                                        \
    }                                                                           \
  }

  int cur = 0;
  for (int t = 0; t < NKT; ++t) {
    char* nb = lds_raw + (cur ^ 65536);                     // staging buffer
    const char* bA = lds_raw + cur + wr * 16384 + lane * 16;
    const char* bB = lds_raw + cur + 32768 + wc * 2048 + lane * 16;
    PH(0, STG_A(0, t + 1, nb), STG_A(2, t + 1, nb), 0)
    PH(1, STG_B(0, t + 1, nb), STG_B(1, t + 1, nb), 1)
    PH(2, STG_A(1, t + 1, nb), STG_A(3, t + 1, nb), 0)
    PH(3, STG_B(2, t + 1, nb), STG_B(3, t + 1, nb), 1)
    cur ^= 65536;
  }
#undef PH
#undef MM
#undef SB
#undef STG_A
#undef STG_B

  // ---- epilogue.  32x32 C/D layout: col = lane&31, row = (r&3)+8*(r>>2)+4*(lane>>5)
  const int rbase = arow0 + wr * 128 + ((lane >> 5) << 2);
  const int cbase = brow0 + wc * 64 + (lane & 31);

  if constexpr (MODE == 1) {
    // packed H write: element (n,c) -> tile (n>>8, c>>6), A-layout within
    char* __restrict__ Hc = (char*)Cout;
    const int kexp = brow0 >> 10;  // expert is block-uniform (256 | 1024)
    float bv[2] = {bias[cbase], bias[cbase + 32]};
    size_t cpart[2];
#pragma unroll
    for (int nj = 0; nj < 2; ++nj) {
      int c = cbase + nj * 32;
      cpart[nj] = (size_t)(c >> 6) * 32768 + ((c >> 4) & 3) * 4096
                + ((c >> 3) & 1) * 512 + (c & 7) * 2;
    }
#pragma unroll
    for (int mi = 0; mi < 4; ++mi)
#pragma unroll
      for (int r = 0; r < 16; ++r) {
        int n = rbase + mi * 32 + (r & 3) + 8 * (r >> 2);
        float wn4 = wgt[(size_t)n * KEXP + kexp];
        size_t npart = (size_t)(n >> 8) * (NKT * 32768) + ((n >> 7) & 1) * 16384
                     + ((n >> 5) & 3) * 1024 + (n & 31) * 16;
#pragma unroll
        for (int nj = 0; nj < 2; ++nj) {
          float x = acc[mi][nj][r] + bv[nj];
          float g = 0.5f * x * (1.f + erff(x * 0.70710678118654752f));  // exact GELU
          *(bf16_t*)(Hc + npart + cpart[nj]) = (bf16_t)(g * wn4);
        }
      }
  } else {
    float* __restrict__ O = (float*)Cout;
    float bc0[KEXP], bc1[KEXP];
#pragma unroll
    for (int k = 0; k < KEXP; ++k) {
      bc0[k] = bias[(size_t)k * NCOLS + cbase];
      bc1[k] = bias[(size_t)k * NCOLS + cbase + 32];
    }
#pragma unroll
    for (int mi = 0; mi < 4; ++mi)
#pragma unroll
      for (int r = 0; r < 16; ++r) {
        int n = rbase + mi * 32 + (r & 3) + 8 * (r >> 2);
        const float4* wp = (const float4*)(wgt + (size_t)n * KEXP);
        float4 wa = wp[0], wb = wp[1];
        float w8[KEXP] = {wa.x, wa.y, wa.z, wa.w, wb.x, wb.y, wb.z, wb.w};
        float s0 = 0.f, s1 = 0.f;
#pragma unroll
        for (int k = 0; k < KEXP; ++k) { s0 += w8[k] * bc0[k]; s1 += w8[k] * bc1[k]; }
        O[(size_t)n * NCOLS + cbase]      = acc[mi][0][r] + s0;
        O[(size_t)n * NCOLS + cbase + 32] = acc[mi][1][r] + s1;
      }
  }
}

extern "C" void kernel_launch(void* const* d_in, const int* in_sizes, int n_in,
                              void* d_out, int out_size, void* d_ws, size_t ws_size,
                              hipStream_t stream) {
  const float* h_anchor = (const float*)d_in[0];
  const float* h_mask   = (const float*)d_in[1];
  const float* Wr       = (const float*)d_in[2];
  const float* br       = (const float*)d_in[3];
  const float* W1       = (const float*)d_in[4];
  const float* b1       = (const float*)d_in[5];
  const float* W2       = (const float*)d_in[6];
  const float* b2       = (const float*)d_in[7];
  float* out = (float*)d_out;

  char* ws = (char*)d_ws;
  bf16_t* Apk  = (bf16_t*)(ws);                       // packed A    128 MB
  bf16_t* B1pk = (bf16_t*)(ws + ((size_t)128 << 20)); // packed W1   128 MB
  bf16_t* B2pk = (bf16_t*)(ws + ((size_t)256 << 20)); // packed W2    64 MB
  bf16_t* Hpk  = (bf16_t*)(ws + ((size_t)320 << 20)); // packed H1s  128 MB
  float*  wgt  = (float*) (ws + ((size_t)448 << 20)); // [8192][8]   256 KB

  routing_kernel<<<N_ROWS, 256, 0, stream>>>(h_mask, Wr, br, wgt);
  pack_cond_kernel<<<32 * 128, 256, 0, stream>>>(h_anchor, h_mask, Apk);
  pack_w1_kernel<<<32 * 128, 256, 0, stream>>>(W1, B1pk);
  pack_w2_kernel<<<16 * 128, 256, 0, stream>>>(W2, B2pk);

  gemm256_kernel<1, 8192><<<(N_ROWS / 256) * (KD / 256), 512, 0, stream>>>(
      Apk, B1pk, (void*)Hpk, b1, wgt);
  gemm256_kernel<2, 4096><<<(N_ROWS / 256) * (DDIM / 256), 512, 0, stream>>>(
      Hpk, B2pk, (void*)out, b2, wgt);
}